// Round 13
// baseline (135.534 us; speedup 1.0000x reference)
//
#include <hip/hip_runtime.h>
#include <math.h>

namespace {

constexpr int IMH = 240, IMW = 320;
constexpr int ER = 120, EC = 160, EH = 8, EW = 16;
constexpr int NG = 384;            // 6*8*8
constexpr int NPIX = ER * EC;      // 19200
constexpr int NB = 2;
constexpr int NTAP = EH * EW;      // 128

// d_out offsets (floats): (env_acc, env_mean, points, mask, vec_to_t)
constexpr size_t ACC_N    = (size_t)NB * 3 * NG * NPIX;
constexpr size_t OFF_ACC  = 0;
constexpr size_t OFF_MEAN = OFF_ACC + ACC_N;
constexpr size_t MEAN_N   = (size_t)NB * NG * 3;
constexpr size_t OFF_PTS  = OFF_MEAN + MEAN_N;
constexpr size_t PTS_N    = (size_t)NB * 3 * IMH * IMW;
constexpr size_t OFF_MASK = OFF_PTS + PTS_N;
constexpr size_t MASK_N   = (size_t)NB * NPIX;
constexpr size_t OFF_VEC  = OFF_MASK + MASK_N;

// k_env geometry: 64 px per block, 512 threads, 1 px/thread, 8 g-lanes
constexpr int TPX   = 64;
constexpr int GLN   = 8;
constexpr int GIT   = NG / GLN;           // 48
constexpr int TILES = NPIX / TPX;         // 300
constexpr int LR01  = 129;                // lds01 stride (dwords)
constexpr int LR2   = 132;                // lds2 stride (shorts)

// d_ws offsets (floats)
constexpr size_t WS_S     = (size_t)NB * NPIX;              // 38400
constexpr size_t WS_INVA  = 0;                              // 9 planes
constexpr size_t WS_PTS   = WS_INVA + 9 * WS_S;             // 3 planes
constexpr size_t WS_PART  = WS_PTS + 3 * WS_S;              // 2304*300 partials
constexpr size_t PART_N   = (size_t)NB * NG * 3 * TILES;    // 691,200
constexpr size_t WS_CNT_HI = WS_PART + PART_N;
constexpr size_t WS_CNT_LO = WS_PART;
constexpr size_t WS_NEED_HI = (WS_CNT_HI + NB) * 4;         // bytes

__device__ __forceinline__ float fpix_of(const float* K, int b) {
    return K[b * 9 + 0] * (IMW * 0.5f) / K[b * 9 + 2];
}

__device__ __forceinline__ unsigned bf16r(float f) {
    unsigned b = __float_as_uint(f);
    return (b + 0x7FFFu + ((b >> 16) & 1u)) >> 16;
}
__device__ __forceinline__ float bfload(unsigned short u) {
    return __uint_as_float((unsigned)u << 16);
}

// DPP add with compile-time control constants
template <int CTRL, int RMASK>
__device__ __forceinline__ float dpp_add(float s) {
    int t = __builtin_amdgcn_update_dpp(0, __float_as_int(s), CTRL, RMASK, 0xf, true);
    return s + __int_as_float(t);
}
// full-wave (64-lane) sum, pure VALU: lane 63 holds the total
__device__ __forceinline__ float wave_sum64(float s) {
    s = dpp_add<0x111, 0xf>(s);   // row_shr:1
    s = dpp_add<0x112, 0xf>(s);   // row_shr:2
    s = dpp_add<0x114, 0xf>(s);   // row_shr:4
    s = dpp_add<0x118, 0xf>(s);   // row_shr:8 -> lane 16k+15 = row sum
    s = dpp_add<0x142, 0xa>(s);   // row_bcast:15 into rows 1,3
    s = dpp_add<0x143, 0xc>(s);   // row_bcast:31 into rows 2,3 -> lane63 total
    return s;
}

// el = acos(x) * 16/pi  (poly coeffs pre-scaled)
__device__ __forceinline__ float acos_el(float x) {
    float ax = fminf(fabsf(x), 1.0f);
    float p  = fmaf(fmaf(fmaf(-0.09538315f, ax, 0.37820512f), ax, -1.08021632f),
                    ax, 7.99996873f);
    float r  = sqrtf(1.0f - ax) * p;
    return (x >= 0.0f) ? r : 16.0f - r;
}

// az = 8 + atan2(y,x)*8/pi  (coeffs pre-scaled)
__device__ __forceinline__ float atan2_az(float y, float x) {
    float ay = fabsf(y), ax = fabsf(x);
    float mn = fminf(ax, ay), mx = fmaxf(ax, ay);
    float a  = mn * __builtin_amdgcn_rcpf(fmaxf(mx, 1e-37f));
    float s  = a * a;
    float r  = a * fmaf(s, fmaf(s, fmaf(s, fmaf(s, 0.05305631f, -0.21677864f),
                                        0.45872349f), -0.84104627f), 2.54613763f);
    if (ay > ax) r = 4.0f - r;
    if (x < 0.0f) r = 8.0f - r;
    return fmaf(copysignf(1.0f, y), r, 8.0f);
}

__global__ void k_points_zero(const float* __restrict__ depth,
                              const float* __restrict__ K,
                              float* __restrict__ out,
                              float* __restrict__ ws, size_t cnt_off) {
    int idx = blockIdx.x * 256 + threadIdx.x;
    if (blockIdx.x == 0 && threadIdx.x < NB) ws[cnt_off + threadIdx.x] = 0.0f;
    if (idx >= NB * IMH * IMW) return;
    int b  = idx / (IMH * IMW);
    int pp = idx - b * (IMH * IMW);
    int v  = pp / IMW;
    int u  = pp - v * IMW;
    float fp = fpix_of(K, b);
    float z  = -depth[idx];
    float x  = -(((float)u - IMW * 0.5f) / fp) * z;
    float y  =  (((float)v - IMH * 0.5f) / fp) * z;
    float* P = out + OFF_PTS + (size_t)b * 3 * IMH * IMW;
    P[pp]                 = x;
    P[pp + IMH * IMW]     = y;
    P[pp + 2 * IMH * IMW] = z;
}

__global__ void k_prep(const float* __restrict__ normal,
                       const float* __restrict__ depth,
                       const float* __restrict__ K,
                       float* __restrict__ out,
                       float* __restrict__ ws, size_t cnt_off) {
    int idx = blockIdx.x * 256 + threadIdx.x;
    if (idx >= NB * NPIX) return;
    int b   = idx / NPIX;
    int pix = idx - b * NPIX;
    int h   = pix / EC;
    int w   = pix - h * EC;
    int v = 2 * h, u = 2 * w;

    float fp = fpix_of(K, b);
    float z  = -depth[(size_t)b * IMH * IMW + (size_t)v * IMW + u];
    float px = -(((float)u - 160.0f) / fp) * z;
    float py =  (((float)v - 120.0f) / fp) * z;

    ws[WS_PTS + 0 * WS_S + idx] = px;
    ws[WS_PTS + 1 * WS_S + idx] = py;
    ws[WS_PTS + 2 * WS_S + idx] = z;

    float m = (z < -0.1f) ? 1.0f : 0.0f;
    out[OFF_MASK + idx] = m;
    float cm = m;
    for (int off = 32; off > 0; off >>= 1) cm += __shfl_down(cm, off);
    if ((threadIdx.x & 63) == 0) atomicAdd(&ws[cnt_off + b], cm);

    float n[3];
#pragma unroll
    for (int c = 0; c < 3; ++c) {
        const float* Nc = normal + ((size_t)(b * 3 + c) * IMH + v) * IMW + u;
        n[c] = 0.25f * (Nc[0] + Nc[1] + Nc[IMW] + Nc[IMW + 1]);
    }
    float nl = sqrtf(n[0]*n[0] + n[1]*n[1] + n[2]*n[2]) + 1e-6f;
    float nx = n[0] / nl, ny = n[1] / nl, nz = n[2] / nl;

    float t0 = -ny * nx, t1 = 1.0f - ny * ny, t2 = -ny * nz;
    float tl = sqrtf(t0*t0 + t1*t1 + t2*t2) + 1e-6f;
    float cy0 = t0 / tl, cy1 = t1 / tl, cy2 = t2 / tl;

    float cr0 = cy1 * nz - cy2 * ny;
    float cr1 = cy2 * nx - cy0 * nz;
    float cr2 = cy0 * ny - cy1 * nx;
    float cl = sqrtf(cr0*cr0 + cr1*cr1 + cr2*cr2) + 1e-6f;
    float cx0 = -cr0 / cl, cx1 = -cr1 / cl, cx2 = -cr2 / cl;

    float a00 = cx0 + 1e-6f, a01 = cy0,         a02 = nx;
    float a10 = cx1,         a11 = cy1 + 1e-6f, a12 = ny;
    float a20 = cx2,         a21 = cy2,         a22 = nz + 1e-6f;

    float c00 =  a11 * a22 - a12 * a21;
    float c01 = -(a10 * a22 - a12 * a20);
    float c02 =  a10 * a21 - a11 * a20;
    float det = a00 * c00 + a01 * c01 + a02 * c02;
    float id  = 1.0f / det;

    ws[WS_INVA + 0 * WS_S + idx] = c00 * id;
    ws[WS_INVA + 1 * WS_S + idx] = (a02 * a21 - a01 * a22) * id;
    ws[WS_INVA + 2 * WS_S + idx] = (a01 * a12 - a02 * a11) * id;
    ws[WS_INVA + 3 * WS_S + idx] = c01 * id;
    ws[WS_INVA + 4 * WS_S + idx] = (a00 * a22 - a02 * a20) * id;
    ws[WS_INVA + 5 * WS_S + idx] = (a02 * a10 - a00 * a12) * id;
    ws[WS_INVA + 6 * WS_S + idx] = c02 * id;
    ws[WS_INVA + 7 * WS_S + idx] = (a01 * a20 - a00 * a21) * id;
    ws[WS_INVA + 8 * WS_S + idx] = (a00 * a11 - a01 * a10) * id;
}

template <bool WP>
__global__ void __launch_bounds__(512, 6) k_env(const float* __restrict__ env,
                       const float* __restrict__ verts,
                       float* __restrict__ out,
                       float* __restrict__ ws) {
    // packed-channel bf16 env tile for 64 px: c0|c1 dwords, c2 shorts. 49.9 KB
    __shared__ unsigned       lds01[TPX * LR01];
    __shared__ unsigned short lds2 [TPX * LR2];

    int blk  = blockIdx.x;
    int b    = blk / TILES;
    int tile = blk - b * TILES;
    int px0  = tile * TPX;
    int t    = threadIdx.x;

    // ---- stage env tile (3ch x 64px x 128 taps), channel-packed ----
    {
        const float* ebase = env + (size_t)b * 3 * NPIX * NTAP + (size_t)px0 * NTAP;
#pragma unroll
        for (int it2 = 0; it2 < 4; ++it2) {
            int idx2 = it2 * 512 + t;          // px (6b) | tapquad (5b)
            int ppx  = idx2 >> 5;
            int tq   = idx2 & 31;
            const float* p0 = ebase + (size_t)ppx * NTAP + tq * 4;
            float4 c0 = *(const float4*)(p0);
            float4 c1 = *(const float4*)(p0 + (size_t)NPIX * NTAP);
            float4 c2 = *(const float4*)(p0 + (size_t)2 * NPIX * NTAP);
#pragma unroll
            for (int k = 0; k < 4; ++k) {
                lds01[ppx * LR01 + tq * 4 + k] =
                    bf16r((&c0.x)[k]) | (bf16r((&c1.x)[k]) << 16);
            }
            ushort4 s4;
            s4.x = (unsigned short)bf16r(c2.x);
            s4.y = (unsigned short)bf16r(c2.y);
            s4.z = (unsigned short)bf16r(c2.z);
            s4.w = (unsigned short)bf16r(c2.w);
            *(ushort4*)(&lds2[ppx * LR2 + tq * 4]) = s4;
        }
    }
    __syncthreads();

    int px_l  = t & 63;          // pixel within tile
    int glane = t >> 6;          // 0..7
    int pix   = px0 + px_l;
    int bp    = b * NPIX + pix;
    int row1  = px_l * LR01;
    int row2  = px_l * LR2;

    float px = ws[WS_PTS + 0 * WS_S + bp];
    float py = ws[WS_PTS + 1 * WS_S + bp];
    float pz = ws[WS_PTS + 2 * WS_S + bp];
    float i00 = ws[WS_INVA + 0 * WS_S + bp];
    float i01 = ws[WS_INVA + 1 * WS_S + bp];
    float i02 = ws[WS_INVA + 2 * WS_S + bp];
    float i10 = ws[WS_INVA + 3 * WS_S + bp];
    float i11 = ws[WS_INVA + 4 * WS_S + bp];
    float i12 = ws[WS_INVA + 5 * WS_S + bp];
    float i20 = ws[WS_INVA + 6 * WS_S + bp];
    float i21 = ws[WS_INVA + 7 * WS_S + bp];
    float i22 = ws[WS_INVA + 8 * WS_S + bp];
    float m = (pz < -0.1f) ? 1.0f : 0.0f;

    int g0 = glane * GIT;
    const float* vp = verts + ((size_t)b * NG + g0) * 3;
    float* pA0 = out + OFF_ACC + ((size_t)(b * 3 + 0) * NG + g0) * NPIX + pix;
    float* pA1 = out + OFF_ACC + ((size_t)(b * 3 + 1) * NG + g0) * NPIX + pix;
    float* pA2 = out + OFF_ACC + ((size_t)(b * 3 + 2) * NG + g0) * NPIX + pix;
    float* pV  = out + OFF_VEC + (((size_t)b * NG + g0) * NPIX + pix) * 3;
    float* pP  = ws + WS_PART + ((size_t)(b * NG + g0) * 3) * TILES + tile;

#pragma unroll 2
    for (int it = 0; it < GIT; ++it) {
        float vx = vp[0] - px, vy = vp[1] - py, vz = vp[2] - pz;
        pV[0] = vx; pV[1] = vy; pV[2] = vz;

        float l0 = i00 * vx + i01 * vy + i02 * vz;
        float l1 = i10 * vx + i11 * vy + i12 * vz;
        float l2 = i20 * vx + i21 * vy + i22 * vz;
        float nl = sqrtf(l0*l0 + l1*l1 + l2*l2) + 1e-6f;
        float l2n = l2 * __builtin_amdgcn_rcpf(nl);

        float el = acos_el(l2n);
        float az = atan2_az(l1, l0);

        float azf = __builtin_amdgcn_fmed3f(az - 0.5f, 0.0f, 15.0f);
        float elf = __builtin_amdgcn_fmed3f(el - 0.5f, 0.0f, 7.0f);
        float x0 = floorf(azf), y0 = floorf(elf);
        float fx = azf - x0,    fy = elf - y0;
        int x0i = (int)x0, y0i = (int)y0;
        int x1i = min(x0i + 1, 15);
        int y1i = min(y0i + 1, 7);

        float w00 = (1.0f - fx) * (1.0f - fy);
        float w01 = fx * (1.0f - fy);
        float w10 = (1.0f - fx) * fy;
        float w11 = fx * fy;

        int t00 = (y0i << 4) + x0i;
        int t01 = (y0i << 4) + x1i;
        int t10 = (y1i << 4) + x0i;
        int t11 = (y1i << 4) + x1i;

        unsigned q00 = lds01[row1 + t00], q01 = lds01[row1 + t01];
        unsigned q10 = lds01[row1 + t10], q11 = lds01[row1 + t11];

        float v0 = (__uint_as_float(q00 << 16) * w00 + __uint_as_float(q01 << 16) * w01 +
                    __uint_as_float(q10 << 16) * w10 + __uint_as_float(q11 << 16) * w11) * m;
        float v1 = (__uint_as_float(q00 & 0xFFFF0000u) * w00 + __uint_as_float(q01 & 0xFFFF0000u) * w01 +
                    __uint_as_float(q10 & 0xFFFF0000u) * w10 + __uint_as_float(q11 & 0xFFFF0000u) * w11) * m;
        float v2 = (bfload(lds2[row2 + t00]) * w00 + bfload(lds2[row2 + t01]) * w01 +
                    bfload(lds2[row2 + t10]) * w10 + bfload(lds2[row2 + t11]) * w11) * m;

        // wave-level stores: 64 contiguous dwords = 256 B per plane
        *pA0 = v0; *pA1 = v1; *pA2 = v2;

        if constexpr (WP) {
            float s0 = wave_sum64(v0);
            float s1 = wave_sum64(v1);
            float s2 = wave_sum64(v2);
            if ((t & 63) == 63) {
                pP[0 * TILES] = s0;
                pP[1 * TILES] = s1;
                pP[2 * TILES] = s2;
            }
            pP += 3 * TILES;
        }

        vp  += 3;
        pV  += (size_t)NPIX * 3;
        pA0 += NPIX; pA1 += NPIX; pA2 += NPIX;
    }
}

// reduce 300 tile-partials per (b,g,c); one wave per output
__global__ void k_psum(float* __restrict__ out, const float* __restrict__ ws,
                       size_t cnt_off) {
    int r = blockIdx.x;                 // (b*NG+g)*3+c
    int l = threadIdx.x;                // 0..63
    const float* p = ws + WS_PART + (size_t)r * TILES;
    float s = 0.0f;
    for (int i = l; i < TILES; i += 64) s += p[i];
#pragma unroll
    for (int off = 32; off > 0; off >>= 1) s += __shfl_down(s, off);
    if (l == 0) {
        int b = r / (NG * 3);
        out[OFF_MEAN + r] = s / (ws[cnt_off + b] + 1e-6f);
    }
}

// fallback: mean via re-read of env_acc (used only if ws too small)
__global__ void k_mean2(float* __restrict__ out, const float* __restrict__ ws,
                        size_t cnt_off) {
    __shared__ float wsum[4];
    int blk = blockIdx.x;                 // (b*3+c)*NG + g
    int b   = blk / (3 * NG);
    int t   = threadIdx.x;

    const float4* r4 = (const float4*)(out + OFF_ACC + (size_t)blk * NPIX);
    float s = 0.0f;
    for (int i = t; i < NPIX / 4; i += 256) {
        float4 v = r4[i];
        s += v.x + v.y + v.z + v.w;
    }
    for (int off = 32; off > 0; off >>= 1) s += __shfl_down(s, off);
    if ((t & 63) == 0) wsum[t >> 6] = s;
    __syncthreads();
    if (t == 0) {
        int rc = blk - b * 3 * NG;
        int c  = rc / NG;
        int g  = rc - c * NG;
        float tot = wsum[0] + wsum[1] + wsum[2] + wsum[3];
        out[OFF_MEAN + ((size_t)b * NG + g) * 3 + c] = tot / (ws[cnt_off + b] + 1e-6f);
    }
}

}  // namespace

extern "C" void kernel_launch(void* const* d_in, const int* in_sizes, int n_in,
                              void* d_out, int out_size, void* d_ws, size_t ws_size,
                              hipStream_t stream) {
    (void)in_sizes; (void)n_in; (void)out_size;
    const float* normalPred = (const float*)d_in[0];
    const float* depthPred  = (const float*)d_in[1];
    const float* env        = (const float*)d_in[2];
    const float* K          = (const float*)d_in[3];
    const float* verts      = (const float*)d_in[4];
    float* out = (float*)d_out;
    float* ws  = (float*)d_ws;

    const bool big = ws_size >= WS_NEED_HI;
    const size_t cnt_off = big ? WS_CNT_HI : WS_CNT_LO;

    k_points_zero<<<(NB * IMH * IMW + 255) / 256, 256, 0, stream>>>(depthPred, K, out, ws, cnt_off);
    k_prep<<<(NB * NPIX + 255) / 256, 256, 0, stream>>>(normalPred, depthPred, K, out, ws, cnt_off);
    if (big) {
        k_env<true><<<NB * TILES, 512, 0, stream>>>(env, verts, out, ws);
        k_psum<<<NB * NG * 3, 64, 0, stream>>>(out, ws, cnt_off);
    } else {
        k_env<false><<<NB * TILES, 512, 0, stream>>>(env, verts, out, ws);
        k_mean2<<<NB * 3 * NG, 256, 0, stream>>>(out, ws, cnt_off);
    }
}

// Round 14
// 121.897 us; speedup vs baseline: 1.1119x; 1.1119x over previous
//
#include <hip/hip_runtime.h>
#include <math.h>

namespace {

constexpr int IMH = 240, IMW = 320;
constexpr int ER = 120, EC = 160, EH = 8, EW = 16;
constexpr int NG = 384;            // 6*8*8
constexpr int NPIX = ER * EC;      // 19200
constexpr int NB = 2;
constexpr int NTAP = EH * EW;      // 128

// d_out offsets (floats): (env_acc, env_mean, points, mask, vec_to_t)
constexpr size_t ACC_N    = (size_t)NB * 3 * NG * NPIX;
constexpr size_t OFF_ACC  = 0;
constexpr size_t OFF_MEAN = OFF_ACC + ACC_N;
constexpr size_t MEAN_N   = (size_t)NB * NG * 3;
constexpr size_t OFF_PTS  = OFF_MEAN + MEAN_N;
constexpr size_t PTS_N    = (size_t)NB * 3 * IMH * IMW;
constexpr size_t OFF_MASK = OFF_PTS + PTS_N;
constexpr size_t MASK_N   = (size_t)NB * NPIX;
constexpr size_t OFF_VEC  = OFF_MASK + MASK_N;

// k_env geometry: 32 px per block (bf16 env tile in LDS), 8 g-lanes,
// INTERLEAVED g-walk: g = it*GLN + glane  (adjacent g across half-waves)
constexpr int TPX   = 32;
constexpr int GLN   = 8;
constexpr int GIT   = NG / GLN;           // 48
constexpr int TILES = NPIX / TPX;         // 600
constexpr int LROW  = 3 * NTAP + 4;       // 388 shorts per px row (24.8 KB tile)

// d_ws offsets (floats)
constexpr size_t WS_S     = (size_t)NB * NPIX;              // 38400
constexpr size_t WS_INVA  = 0;                              // 9 planes
constexpr size_t WS_PTS   = WS_INVA + 9 * WS_S;             // 3 planes
constexpr size_t WS_PART  = WS_PTS + 3 * WS_S;              // 2304*600 partials
constexpr size_t PART_N   = (size_t)NB * NG * 3 * TILES;    // 1,382,400
constexpr size_t WS_CNT_HI = WS_PART + PART_N;
constexpr size_t WS_CNT_LO = WS_PART;
constexpr size_t WS_NEED_HI = (WS_CNT_HI + NB) * 4;         // bytes

__device__ __forceinline__ float fpix_of(const float* K, int b) {
    return K[b * 9 + 0] * (IMW * 0.5f) / K[b * 9 + 2];
}

__device__ __forceinline__ unsigned bf16r(float f) {
    unsigned b = __float_as_uint(f);
    return (b + 0x7FFFu + ((b >> 16) & 1u)) >> 16;
}
__device__ __forceinline__ float bfload(unsigned short u) {
    return __uint_as_float((unsigned)u << 16);
}

// DPP add with compile-time control constants
template <int CTRL, int RMASK>
__device__ __forceinline__ float dpp_add(float s) {
    int t = __builtin_amdgcn_update_dpp(0, __float_as_int(s), CTRL, RMASK, 0xf, true);
    return s + __int_as_float(t);
}
// half-wave (32-lane) sum, pure VALU: result in lanes 31 and 63
__device__ __forceinline__ float hw_sum(float s) {
    s = dpp_add<0x111, 0xf>(s);   // row_shr:1
    s = dpp_add<0x112, 0xf>(s);   // row_shr:2
    s = dpp_add<0x114, 0xf>(s);   // row_shr:4
    s = dpp_add<0x118, 0xf>(s);   // row_shr:8 -> lane15/31/47/63 = row sums
    s = dpp_add<0x142, 0xa>(s);   // row_bcast:15 into rows 1,3
    return s;                     // lane31 = rows0+1, lane63 = rows2+3
}

// el = acos(x) * 16/pi  (poly coeffs pre-scaled)
__device__ __forceinline__ float acos_el(float x) {
    float ax = fminf(fabsf(x), 1.0f);
    float p  = fmaf(fmaf(fmaf(-0.09538315f, ax, 0.37820512f), ax, -1.08021632f),
                    ax, 7.99996873f);
    float r  = sqrtf(1.0f - ax) * p;
    return (x >= 0.0f) ? r : 16.0f - r;
}

// az = 8 + atan2(y,x)*8/pi  (coeffs pre-scaled)
__device__ __forceinline__ float atan2_az(float y, float x) {
    float ay = fabsf(y), ax = fabsf(x);
    float mn = fminf(ax, ay), mx = fmaxf(ax, ay);
    float a  = mn * __builtin_amdgcn_rcpf(fmaxf(mx, 1e-37f));
    float s  = a * a;
    float r  = a * fmaf(s, fmaf(s, fmaf(s, fmaf(s, 0.05305631f, -0.21677864f),
                                        0.45872349f), -0.84104627f), 2.54613763f);
    if (ay > ax) r = 4.0f - r;
    if (x < 0.0f) r = 8.0f - r;
    return fmaf(copysignf(1.0f, y), r, 8.0f);
}

__global__ void k_points_zero(const float* __restrict__ depth,
                              const float* __restrict__ K,
                              float* __restrict__ out,
                              float* __restrict__ ws, size_t cnt_off) {
    int idx = blockIdx.x * 256 + threadIdx.x;
    if (blockIdx.x == 0 && threadIdx.x < NB) ws[cnt_off + threadIdx.x] = 0.0f;
    if (idx >= NB * IMH * IMW) return;
    int b  = idx / (IMH * IMW);
    int pp = idx - b * (IMH * IMW);
    int v  = pp / IMW;
    int u  = pp - v * IMW;
    float fp = fpix_of(K, b);
    float z  = -depth[idx];
    float x  = -(((float)u - IMW * 0.5f) / fp) * z;
    float y  =  (((float)v - IMH * 0.5f) / fp) * z;
    float* P = out + OFF_PTS + (size_t)b * 3 * IMH * IMW;
    P[pp]                 = x;
    P[pp + IMH * IMW]     = y;
    P[pp + 2 * IMH * IMW] = z;
}

__global__ void k_prep(const float* __restrict__ normal,
                       const float* __restrict__ depth,
                       const float* __restrict__ K,
                       float* __restrict__ out,
                       float* __restrict__ ws, size_t cnt_off) {
    int idx = blockIdx.x * 256 + threadIdx.x;
    if (idx >= NB * NPIX) return;
    int b   = idx / NPIX;
    int pix = idx - b * NPIX;
    int h   = pix / EC;
    int w   = pix - h * EC;
    int v = 2 * h, u = 2 * w;

    float fp = fpix_of(K, b);
    float z  = -depth[(size_t)b * IMH * IMW + (size_t)v * IMW + u];
    float px = -(((float)u - 160.0f) / fp) * z;
    float py =  (((float)v - 120.0f) / fp) * z;

    ws[WS_PTS + 0 * WS_S + idx] = px;
    ws[WS_PTS + 1 * WS_S + idx] = py;
    ws[WS_PTS + 2 * WS_S + idx] = z;

    float m = (z < -0.1f) ? 1.0f : 0.0f;
    out[OFF_MASK + idx] = m;
    float cm = m;
    for (int off = 32; off > 0; off >>= 1) cm += __shfl_down(cm, off);
    if ((threadIdx.x & 63) == 0) atomicAdd(&ws[cnt_off + b], cm);

    float n[3];
#pragma unroll
    for (int c = 0; c < 3; ++c) {
        const float* Nc = normal + ((size_t)(b * 3 + c) * IMH + v) * IMW + u;
        n[c] = 0.25f * (Nc[0] + Nc[1] + Nc[IMW] + Nc[IMW + 1]);
    }
    float nl = sqrtf(n[0]*n[0] + n[1]*n[1] + n[2]*n[2]) + 1e-6f;
    float nx = n[0] / nl, ny = n[1] / nl, nz = n[2] / nl;

    float t0 = -ny * nx, t1 = 1.0f - ny * ny, t2 = -ny * nz;
    float tl = sqrtf(t0*t0 + t1*t1 + t2*t2) + 1e-6f;
    float cy0 = t0 / tl, cy1 = t1 / tl, cy2 = t2 / tl;

    float cr0 = cy1 * nz - cy2 * ny;
    float cr1 = cy2 * nx - cy0 * nz;
    float cr2 = cy0 * ny - cy1 * nx;
    float cl = sqrtf(cr0*cr0 + cr1*cr1 + cr2*cr2) + 1e-6f;
    float cx0 = -cr0 / cl, cx1 = -cr1 / cl, cx2 = -cr2 / cl;

    float a00 = cx0 + 1e-6f, a01 = cy0,         a02 = nx;
    float a10 = cx1,         a11 = cy1 + 1e-6f, a12 = ny;
    float a20 = cx2,         a21 = cy2,         a22 = nz + 1e-6f;

    float c00 =  a11 * a22 - a12 * a21;
    float c01 = -(a10 * a22 - a12 * a20);
    float c02 =  a10 * a21 - a11 * a20;
    float det = a00 * c00 + a01 * c01 + a02 * c02;
    float id  = 1.0f / det;

    ws[WS_INVA + 0 * WS_S + idx] = c00 * id;
    ws[WS_INVA + 1 * WS_S + idx] = (a02 * a21 - a01 * a22) * id;
    ws[WS_INVA + 2 * WS_S + idx] = (a01 * a12 - a02 * a11) * id;
    ws[WS_INVA + 3 * WS_S + idx] = c01 * id;
    ws[WS_INVA + 4 * WS_S + idx] = (a00 * a22 - a02 * a20) * id;
    ws[WS_INVA + 5 * WS_S + idx] = (a02 * a10 - a00 * a12) * id;
    ws[WS_INVA + 6 * WS_S + idx] = c02 * id;
    ws[WS_INVA + 7 * WS_S + idx] = (a01 * a20 - a00 * a21) * id;
    ws[WS_INVA + 8 * WS_S + idx] = (a00 * a11 - a01 * a10) * id;
}

template <bool WP>
__global__ void __launch_bounds__(256) k_env(const float* __restrict__ env,
                       const float* __restrict__ verts,
                       float* __restrict__ out,
                       float* __restrict__ ws) {
    __shared__ unsigned short lds16[TPX * LROW];   // bf16 env tile, 24.8 KB

    int blk  = blockIdx.x;
    int b    = blk / TILES;
    int tile = blk - b * TILES;
    int px0  = tile * TPX;
    int t    = threadIdx.x;

    // ---- stage env tile (3ch x 32px x 128 taps) as bf16 ----
    {
        const float* ebase = env + (size_t)b * 3 * NPIX * NTAP + (size_t)px0 * NTAP;
#pragma unroll
        for (int it = 0; it < 12; ++it) {
            int f   = (it * 256 + t) * 4;      // dword index in tile
            int c   = f >> 12;
            int r   = f & 4095;
            float4 v4 = *(const float4*)(ebase + (size_t)c * NPIX * NTAP + r);
            ushort4 u4;
            u4.x = (unsigned short)bf16r(v4.x); u4.y = (unsigned short)bf16r(v4.y);
            u4.z = (unsigned short)bf16r(v4.z); u4.w = (unsigned short)bf16r(v4.w);
            int j   = r >> 7;
            int tap = r & 127;
            *(ushort4*)(&lds16[j * LROW + c * NTAP + tap]) = u4;
        }
    }
    __syncthreads();

    int px_l  = t & 31;
    int glane = t >> 5;          // 0..7
    int pix   = px0 + px_l;
    int bp    = b * NPIX + pix;
    int row   = px_l * LROW;

    float px = ws[WS_PTS + 0 * WS_S + bp];
    float py = ws[WS_PTS + 1 * WS_S + bp];
    float pz = ws[WS_PTS + 2 * WS_S + bp];
    float i00 = ws[WS_INVA + 0 * WS_S + bp];
    float i01 = ws[WS_INVA + 1 * WS_S + bp];
    float i02 = ws[WS_INVA + 2 * WS_S + bp];
    float i10 = ws[WS_INVA + 3 * WS_S + bp];
    float i11 = ws[WS_INVA + 4 * WS_S + bp];
    float i12 = ws[WS_INVA + 5 * WS_S + bp];
    float i20 = ws[WS_INVA + 6 * WS_S + bp];
    float i21 = ws[WS_INVA + 7 * WS_S + bp];
    float i22 = ws[WS_INVA + 8 * WS_S + bp];
    float m = (pz < -0.1f) ? 1.0f : 0.0f;

    // INTERLEAVED g-walk: g = it*GLN + glane. The block's 8 half-waves write
    // 8 ADJACENT g-planes at every step -> contiguous MB-scale write fronts
    // (DRAM row locality) instead of 8 scattered g-windows.
    int g0 = glane;
    const float* vp = verts + ((size_t)b * NG + g0) * 3;
    float* pA0 = out + OFF_ACC + ((size_t)(b * 3 + 0) * NG + g0) * NPIX + pix;
    float* pA1 = out + OFF_ACC + ((size_t)(b * 3 + 1) * NG + g0) * NPIX + pix;
    float* pA2 = out + OFF_ACC + ((size_t)(b * 3 + 2) * NG + g0) * NPIX + pix;
    float* pV  = out + OFF_VEC + (((size_t)b * NG + g0) * NPIX + pix) * 3;
    float* pP  = ws + WS_PART + ((size_t)(b * NG + g0) * 3) * TILES + tile;

#pragma unroll 2
    for (int it = 0; it < GIT; ++it) {
        float vx = vp[0] - px, vy = vp[1] - py, vz = vp[2] - pz;
        pV[0] = vx; pV[1] = vy; pV[2] = vz;

        float l0 = i00 * vx + i01 * vy + i02 * vz;
        float l1 = i10 * vx + i11 * vy + i12 * vz;
        float l2 = i20 * vx + i21 * vy + i22 * vz;
        float nl = sqrtf(l0*l0 + l1*l1 + l2*l2) + 1e-6f;
        float l2n = l2 * __builtin_amdgcn_rcpf(nl);

        float el = acos_el(l2n);             // theta in grid units
        float az = atan2_az(l1, l0);         // phi in grid units

        float azf = __builtin_amdgcn_fmed3f(az - 0.5f, 0.0f, 15.0f);
        float elf = __builtin_amdgcn_fmed3f(el - 0.5f, 0.0f, 7.0f);
        float x0 = floorf(azf), y0 = floorf(elf);
        float fx = azf - x0,    fy = elf - y0;
        int x0i = (int)x0, y0i = (int)y0;
        int x1i = min(x0i + 1, 15);
        int y1i = min(y0i + 1, 7);

        float w00 = (1.0f - fx) * (1.0f - fy);
        float w01 = fx * (1.0f - fy);
        float w10 = (1.0f - fx) * fy;
        float w11 = fx * fy;

        int a00 = row + (y0i << 4) + x0i;
        int a01 = row + (y0i << 4) + x1i;
        int a10 = row + (y1i << 4) + x0i;
        int a11 = row + (y1i << 4) + x1i;

        float v0 = (bfload(lds16[a00]) * w00 + bfload(lds16[a01]) * w01 +
                    bfload(lds16[a10]) * w10 + bfload(lds16[a11]) * w11) * m;
        float v1 = (bfload(lds16[a00 + NTAP]) * w00 + bfload(lds16[a01 + NTAP]) * w01 +
                    bfload(lds16[a10 + NTAP]) * w10 + bfload(lds16[a11 + NTAP]) * w11) * m;
        float v2 = (bfload(lds16[a00 + 2*NTAP]) * w00 + bfload(lds16[a01 + 2*NTAP]) * w01 +
                    bfload(lds16[a10 + 2*NTAP]) * w10 + bfload(lds16[a11 + 2*NTAP]) * w11) * m;

        *pA0 = v0; *pA1 = v1; *pA2 = v2;

        if constexpr (WP) {
            // half-wave pixel-sum via DPP (pure VALU); partials to unique slots
            float s0 = hw_sum(v0);
            float s1 = hw_sum(v1);
            float s2 = hw_sum(v2);
            if ((t & 31) == 31) {
                pP[0 * TILES] = s0;
                pP[1 * TILES] = s1;
                pP[2 * TILES] = s2;
            }
            pP += (size_t)GLN * 3 * TILES;
        }

        vp  += 3 * GLN;
        pV  += (size_t)GLN * NPIX * 3;
        pA0 += (size_t)GLN * NPIX;
        pA1 += (size_t)GLN * NPIX;
        pA2 += (size_t)GLN * NPIX;
    }
}

// reduce 600 tile-partials per (b,g,c); one wave per output
__global__ void k_psum(float* __restrict__ out, const float* __restrict__ ws,
                       size_t cnt_off) {
    int r = blockIdx.x;                 // (b*NG+g)*3+c
    int l = threadIdx.x;                // 0..63
    const float* p = ws + WS_PART + (size_t)r * TILES;
    float s = 0.0f;
    for (int i = l; i < TILES; i += 64) s += p[i];
#pragma unroll
    for (int off = 32; off > 0; off >>= 1) s += __shfl_down(s, off);
    if (l == 0) {
        int b = r / (NG * 3);
        out[OFF_MEAN + r] = s / (ws[cnt_off + b] + 1e-6f);
    }
}

// fallback: mean via re-read of env_acc (used only if ws too small)
__global__ void k_mean2(float* __restrict__ out, const float* __restrict__ ws,
                        size_t cnt_off) {
    __shared__ float wsum[4];
    int blk = blockIdx.x;                 // (b*3+c)*NG + g
    int b   = blk / (3 * NG);
    int t   = threadIdx.x;

    const float4* r4 = (const float4*)(out + OFF_ACC + (size_t)blk * NPIX);
    float s = 0.0f;
    for (int i = t; i < NPIX / 4; i += 256) {
        float4 v = r4[i];
        s += v.x + v.y + v.z + v.w;
    }
    for (int off = 32; off > 0; off >>= 1) s += __shfl_down(s, off);
    if ((t & 63) == 0) wsum[t >> 6] = s;
    __syncthreads();
    if (t == 0) {
        int rc = blk - b * 3 * NG;
        int c  = rc / NG;
        int g  = rc - c * NG;
        float tot = wsum[0] + wsum[1] + wsum[2] + wsum[3];
        out[OFF_MEAN + ((size_t)b * NG + g) * 3 + c] = tot / (ws[cnt_off + b] + 1e-6f);
    }
}

}  // namespace

extern "C" void kernel_launch(void* const* d_in, const int* in_sizes, int n_in,
                              void* d_out, int out_size, void* d_ws, size_t ws_size,
                              hipStream_t stream) {
    (void)in_sizes; (void)n_in; (void)out_size;
    const float* normalPred = (const float*)d_in[0];
    const float* depthPred  = (const float*)d_in[1];
    const float* env        = (const float*)d_in[2];
    const float* K          = (const float*)d_in[3];
    const float* verts      = (const float*)d_in[4];
    float* out = (float*)d_out;
    float* ws  = (float*)d_ws;

    const bool big = ws_size >= WS_NEED_HI;
    const size_t cnt_off = big ? WS_CNT_HI : WS_CNT_LO;

    k_points_zero<<<(NB * IMH * IMW + 255) / 256, 256, 0, stream>>>(depthPred, K, out, ws, cnt_off);
    k_prep<<<(NB * NPIX + 255) / 256, 256, 0, stream>>>(normalPred, depthPred, K, out, ws, cnt_off);
    if (big) {
        k_env<true><<<NB * TILES, 256, 0, stream>>>(env, verts, out, ws);
        k_psum<<<NB * NG * 3, 64, 0, stream>>>(out, ws, cnt_off);
    } else {
        k_env<false><<<NB * TILES, 256, 0, stream>>>(env, verts, out, ws);
        k_mean2<<<NB * 3 * NG, 256, 0, stream>>>(out, ws, cnt_off);
    }
}

// Round 15
// 110.303 us; speedup vs baseline: 1.2287x; 1.1051x over previous
//
#include <hip/hip_runtime.h>
#include <math.h>

namespace {

constexpr int IMH = 240, IMW = 320;
constexpr int ER = 120, EC = 160, EH = 8, EW = 16;
constexpr int NG = 384;            // 6*8*8
constexpr int NPIX = ER * EC;      // 19200
constexpr int NB = 2;
constexpr int NTAP = EH * EW;      // 128

// d_out offsets (floats): (env_acc, env_mean, points, mask, vec_to_t)
constexpr size_t ACC_N    = (size_t)NB * 3 * NG * NPIX;
constexpr size_t OFF_ACC  = 0;
constexpr size_t OFF_MEAN = OFF_ACC + ACC_N;
constexpr size_t MEAN_N   = (size_t)NB * NG * 3;
constexpr size_t OFF_PTS  = OFF_MEAN + MEAN_N;
constexpr size_t PTS_N    = (size_t)NB * 3 * IMH * IMW;
constexpr size_t OFF_MASK = OFF_PTS + PTS_N;
constexpr size_t MASK_N   = (size_t)NB * NPIX;
constexpr size_t OFF_VEC  = OFF_MASK + MASK_N;

// k_env geometry: 32 px per block (bf16 env tile in LDS), 8 g-lanes,
// interleaved g-walk (g = it*GLN + glane) — r14's best structure
constexpr int TPX   = 32;
constexpr int GLN   = 8;
constexpr int GIT   = NG / GLN;           // 48
constexpr int TILES = NPIX / TPX;         // 600
constexpr int LROW  = 3 * NTAP + 4;       // 388 shorts per px row (24.8 KB tile)

// d_ws offsets (floats)
constexpr size_t WS_S     = (size_t)NB * NPIX;              // 38400
constexpr size_t WS_INVA  = 0;                              // 9 planes
constexpr size_t WS_PTS   = WS_INVA + 9 * WS_S;             // 3 planes
constexpr size_t WS_PART  = WS_PTS + 3 * WS_S;              // 2304*600 partials
constexpr size_t PART_N   = (size_t)NB * NG * 3 * TILES;    // 1,382,400
constexpr size_t WS_CNT_HI = WS_PART + PART_N;
constexpr size_t WS_CNT_LO = WS_PART;
constexpr size_t WS_NEED_HI = (WS_CNT_HI + NB) * 4;         // bytes

__device__ __forceinline__ float fpix_of(const float* K, int b) {
    return K[b * 9 + 0] * (IMW * 0.5f) / K[b * 9 + 2];
}

__device__ __forceinline__ unsigned bf16r(float f) {
    unsigned b = __float_as_uint(f);
    return (b + 0x7FFFu + ((b >> 16) & 1u)) >> 16;
}
__device__ __forceinline__ float bfload(unsigned short u) {
    return __uint_as_float((unsigned)u << 16);
}

// DPP add with compile-time control constants
template <int CTRL, int RMASK>
__device__ __forceinline__ float dpp_add(float s) {
    int t = __builtin_amdgcn_update_dpp(0, __float_as_int(s), CTRL, RMASK, 0xf, true);
    return s + __int_as_float(t);
}
// half-wave (32-lane) sum, pure VALU: result in lanes 31 and 63
__device__ __forceinline__ float hw_sum(float s) {
    s = dpp_add<0x111, 0xf>(s);   // row_shr:1
    s = dpp_add<0x112, 0xf>(s);   // row_shr:2
    s = dpp_add<0x114, 0xf>(s);   // row_shr:4
    s = dpp_add<0x118, 0xf>(s);   // row_shr:8 -> lane15/31/47/63 = row sums
    s = dpp_add<0x142, 0xa>(s);   // row_bcast:15 into rows 1,3
    return s;                     // lane31 = rows0+1, lane63 = rows2+3
}

// el = acos(x) * 16/pi  (poly coeffs pre-scaled)
__device__ __forceinline__ float acos_el(float x) {
    float ax = fminf(fabsf(x), 1.0f);
    float p  = fmaf(fmaf(fmaf(-0.09538315f, ax, 0.37820512f), ax, -1.08021632f),
                    ax, 7.99996873f);
    float r  = sqrtf(1.0f - ax) * p;
    return (x >= 0.0f) ? r : 16.0f - r;
}

// az = 8 + atan2(y,x)*8/pi  (coeffs pre-scaled)
__device__ __forceinline__ float atan2_az(float y, float x) {
    float ay = fabsf(y), ax = fabsf(x);
    float mn = fminf(ax, ay), mx = fmaxf(ax, ay);
    float a  = mn * __builtin_amdgcn_rcpf(fmaxf(mx, 1e-37f));
    float s  = a * a;
    float r  = a * fmaf(s, fmaf(s, fmaf(s, fmaf(s, 0.05305631f, -0.21677864f),
                                        0.45872349f), -0.84104627f), 2.54613763f);
    if (ay > ax) r = 4.0f - r;
    if (x < 0.0f) r = 8.0f - r;
    return fmaf(copysignf(1.0f, y), r, 8.0f);
}

__global__ void k_points_zero(const float* __restrict__ depth,
                              const float* __restrict__ K,
                              float* __restrict__ out,
                              float* __restrict__ ws, size_t cnt_off) {
    int idx = blockIdx.x * 256 + threadIdx.x;
    if (blockIdx.x == 0 && threadIdx.x < NB) ws[cnt_off + threadIdx.x] = 0.0f;
    if (idx >= NB * IMH * IMW) return;
    int b  = idx / (IMH * IMW);
    int pp = idx - b * (IMH * IMW);
    int v  = pp / IMW;
    int u  = pp - v * IMW;
    float fp = fpix_of(K, b);
    float z  = -depth[idx];
    float x  = -(((float)u - IMW * 0.5f) / fp) * z;
    float y  =  (((float)v - IMH * 0.5f) / fp) * z;
    float* P = out + OFF_PTS + (size_t)b * 3 * IMH * IMW;
    P[pp]                 = x;
    P[pp + IMH * IMW]     = y;
    P[pp + 2 * IMH * IMW] = z;
}

__global__ void k_prep(const float* __restrict__ normal,
                       const float* __restrict__ depth,
                       const float* __restrict__ K,
                       float* __restrict__ out,
                       float* __restrict__ ws, size_t cnt_off) {
    int idx = blockIdx.x * 256 + threadIdx.x;
    if (idx >= NB * NPIX) return;
    int b   = idx / NPIX;
    int pix = idx - b * NPIX;
    int h   = pix / EC;
    int w   = pix - h * EC;
    int v = 2 * h, u = 2 * w;

    float fp = fpix_of(K, b);
    float z  = -depth[(size_t)b * IMH * IMW + (size_t)v * IMW + u];
    float px = -(((float)u - 160.0f) / fp) * z;
    float py =  (((float)v - 120.0f) / fp) * z;

    ws[WS_PTS + 0 * WS_S + idx] = px;
    ws[WS_PTS + 1 * WS_S + idx] = py;
    ws[WS_PTS + 2 * WS_S + idx] = z;

    float m = (z < -0.1f) ? 1.0f : 0.0f;
    out[OFF_MASK + idx] = m;
    float cm = m;
    for (int off = 32; off > 0; off >>= 1) cm += __shfl_down(cm, off);
    if ((threadIdx.x & 63) == 0) atomicAdd(&ws[cnt_off + b], cm);

    float n[3];
#pragma unroll
    for (int c = 0; c < 3; ++c) {
        const float* Nc = normal + ((size_t)(b * 3 + c) * IMH + v) * IMW + u;
        n[c] = 0.25f * (Nc[0] + Nc[1] + Nc[IMW] + Nc[IMW + 1]);
    }
    float nl = sqrtf(n[0]*n[0] + n[1]*n[1] + n[2]*n[2]) + 1e-6f;
    float nx = n[0] / nl, ny = n[1] / nl, nz = n[2] / nl;

    float t0 = -ny * nx, t1 = 1.0f - ny * ny, t2 = -ny * nz;
    float tl = sqrtf(t0*t0 + t1*t1 + t2*t2) + 1e-6f;
    float cy0 = t0 / tl, cy1 = t1 / tl, cy2 = t2 / tl;

    float cr0 = cy1 * nz - cy2 * ny;
    float cr1 = cy2 * nx - cy0 * nz;
    float cr2 = cy0 * ny - cy1 * nx;
    float cl = sqrtf(cr0*cr0 + cr1*cr1 + cr2*cr2) + 1e-6f;
    float cx0 = -cr0 / cl, cx1 = -cr1 / cl, cx2 = -cr2 / cl;

    float a00 = cx0 + 1e-6f, a01 = cy0,         a02 = nx;
    float a10 = cx1,         a11 = cy1 + 1e-6f, a12 = ny;
    float a20 = cx2,         a21 = cy2,         a22 = nz + 1e-6f;

    float c00 =  a11 * a22 - a12 * a21;
    float c01 = -(a10 * a22 - a12 * a20);
    float c02 =  a10 * a21 - a11 * a20;
    float det = a00 * c00 + a01 * c01 + a02 * c02;
    float id  = 1.0f / det;

    ws[WS_INVA + 0 * WS_S + idx] = c00 * id;
    ws[WS_INVA + 1 * WS_S + idx] = (a02 * a21 - a01 * a22) * id;
    ws[WS_INVA + 2 * WS_S + idx] = (a01 * a12 - a02 * a11) * id;
    ws[WS_INVA + 3 * WS_S + idx] = c01 * id;
    ws[WS_INVA + 4 * WS_S + idx] = (a00 * a22 - a02 * a20) * id;
    ws[WS_INVA + 5 * WS_S + idx] = (a02 * a10 - a00 * a12) * id;
    ws[WS_INVA + 6 * WS_S + idx] = c02 * id;
    ws[WS_INVA + 7 * WS_S + idx] = (a01 * a20 - a00 * a21) * id;
    ws[WS_INVA + 8 * WS_S + idx] = (a00 * a11 - a01 * a10) * id;
}

template <bool WP>
__global__ void __launch_bounds__(256) k_env(const float* __restrict__ env,
                       const float* __restrict__ verts,
                       float* __restrict__ out,
                       float* __restrict__ ws) {
    __shared__ unsigned short lds16[TPX * LROW];   // bf16 env tile, 24.8 KB

    int blk  = blockIdx.x;
    int b    = blk / TILES;
    int tile = blk - b * TILES;
    int px0  = tile * TPX;
    int t    = threadIdx.x;

    // ---- stage env tile (3ch x 32px x 128 taps) as bf16 ----
    {
        const float* ebase = env + (size_t)b * 3 * NPIX * NTAP + (size_t)px0 * NTAP;
#pragma unroll
        for (int it = 0; it < 12; ++it) {
            int f   = (it * 256 + t) * 4;      // dword index in tile
            int c   = f >> 12;
            int r   = f & 4095;
            float4 v4 = *(const float4*)(ebase + (size_t)c * NPIX * NTAP + r);
            ushort4 u4;
            u4.x = (unsigned short)bf16r(v4.x); u4.y = (unsigned short)bf16r(v4.y);
            u4.z = (unsigned short)bf16r(v4.z); u4.w = (unsigned short)bf16r(v4.w);
            int j   = r >> 7;
            int tap = r & 127;
            *(ushort4*)(&lds16[j * LROW + c * NTAP + tap]) = u4;
        }
    }
    __syncthreads();

    int px_l  = t & 31;
    int glane = t >> 5;          // 0..7
    int pix   = px0 + px_l;
    int bp    = b * NPIX + pix;
    int row   = px_l * LROW;

    float px = ws[WS_PTS + 0 * WS_S + bp];
    float py = ws[WS_PTS + 1 * WS_S + bp];
    float pz = ws[WS_PTS + 2 * WS_S + bp];
    float i00 = ws[WS_INVA + 0 * WS_S + bp];
    float i01 = ws[WS_INVA + 1 * WS_S + bp];
    float i02 = ws[WS_INVA + 2 * WS_S + bp];
    float i10 = ws[WS_INVA + 3 * WS_S + bp];
    float i11 = ws[WS_INVA + 4 * WS_S + bp];
    float i12 = ws[WS_INVA + 5 * WS_S + bp];
    float i20 = ws[WS_INVA + 6 * WS_S + bp];
    float i21 = ws[WS_INVA + 7 * WS_S + bp];
    float i22 = ws[WS_INVA + 8 * WS_S + bp];
    float m = (pz < -0.1f) ? 1.0f : 0.0f;

    // interleaved g-walk (r14): 8 half-waves cover 8 adjacent g-planes
    int g0 = glane;
    const float* vp = verts + ((size_t)b * NG + g0) * 3;
    float* pA0 = out + OFF_ACC + ((size_t)(b * 3 + 0) * NG + g0) * NPIX + pix;
    float* pA1 = out + OFF_ACC + ((size_t)(b * 3 + 1) * NG + g0) * NPIX + pix;
    float* pA2 = out + OFF_ACC + ((size_t)(b * 3 + 2) * NG + g0) * NPIX + pix;
    float* pV  = out + OFF_VEC + (((size_t)b * NG + g0) * NPIX + pix) * 3;
    float* pP  = ws + WS_PART + ((size_t)(b * NG + g0) * 3) * TILES + tile;

#pragma unroll 2
    for (int it = 0; it < GIT; ++it) {
        float vx = vp[0] - px, vy = vp[1] - py, vz = vp[2] - pz;
        // nontemporal: vec_to_t is never re-read -> skip L2 write-allocate
        __builtin_nontemporal_store(vx, pV + 0);
        __builtin_nontemporal_store(vy, pV + 1);
        __builtin_nontemporal_store(vz, pV + 2);

        float l0 = i00 * vx + i01 * vy + i02 * vz;
        float l1 = i10 * vx + i11 * vy + i12 * vz;
        float l2 = i20 * vx + i21 * vy + i22 * vz;
        float nl = sqrtf(l0*l0 + l1*l1 + l2*l2) + 1e-6f;
        float l2n = l2 * __builtin_amdgcn_rcpf(nl);

        float el = acos_el(l2n);             // theta in grid units
        float az = atan2_az(l1, l0);         // phi in grid units

        float azf = __builtin_amdgcn_fmed3f(az - 0.5f, 0.0f, 15.0f);
        float elf = __builtin_amdgcn_fmed3f(el - 0.5f, 0.0f, 7.0f);
        float x0 = floorf(azf), y0 = floorf(elf);
        float fx = azf - x0,    fy = elf - y0;
        int x0i = (int)x0, y0i = (int)y0;
        int x1i = min(x0i + 1, 15);
        int y1i = min(y0i + 1, 7);

        float w00 = (1.0f - fx) * (1.0f - fy);
        float w01 = fx * (1.0f - fy);
        float w10 = (1.0f - fx) * fy;
        float w11 = fx * fy;

        int a00 = row + (y0i << 4) + x0i;
        int a01 = row + (y0i << 4) + x1i;
        int a10 = row + (y1i << 4) + x0i;
        int a11 = row + (y1i << 4) + x1i;

        float v0 = (bfload(lds16[a00]) * w00 + bfload(lds16[a01]) * w01 +
                    bfload(lds16[a10]) * w10 + bfload(lds16[a11]) * w11) * m;
        float v1 = (bfload(lds16[a00 + NTAP]) * w00 + bfload(lds16[a01 + NTAP]) * w01 +
                    bfload(lds16[a10 + NTAP]) * w10 + bfload(lds16[a11 + NTAP]) * w11) * m;
        float v2 = (bfload(lds16[a00 + 2*NTAP]) * w00 + bfload(lds16[a01 + 2*NTAP]) * w01 +
                    bfload(lds16[a10 + 2*NTAP]) * w10 + bfload(lds16[a11 + 2*NTAP]) * w11) * m;

        __builtin_nontemporal_store(v0, pA0);
        __builtin_nontemporal_store(v1, pA1);
        __builtin_nontemporal_store(v2, pA2);

        if constexpr (WP) {
            // half-wave pixel-sum via DPP (pure VALU); partials to unique slots
            float s0 = hw_sum(v0);
            float s1 = hw_sum(v1);
            float s2 = hw_sum(v2);
            if ((t & 31) == 31) {
                pP[0 * TILES] = s0;
                pP[1 * TILES] = s1;
                pP[2 * TILES] = s2;
            }
            pP += (size_t)GLN * 3 * TILES;
        }

        vp  += 3 * GLN;
        pV  += (size_t)GLN * NPIX * 3;
        pA0 += (size_t)GLN * NPIX;
        pA1 += (size_t)GLN * NPIX;
        pA2 += (size_t)GLN * NPIX;
    }
}

// reduce 600 tile-partials per (b,g,c); one wave per output
__global__ void k_psum(float* __restrict__ out, const float* __restrict__ ws,
                       size_t cnt_off) {
    int r = blockIdx.x;                 // (b*NG+g)*3+c
    int l = threadIdx.x;                // 0..63
    const float* p = ws + WS_PART + (size_t)r * TILES;
    float s = 0.0f;
    for (int i = l; i < TILES; i += 64) s += p[i];
#pragma unroll
    for (int off = 32; off > 0; off >>= 1) s += __shfl_down(s, off);
    if (l == 0) {
        int b = r / (NG * 3);
        out[OFF_MEAN + r] = s / (ws[cnt_off + b] + 1e-6f);
    }
}

// fallback: mean via re-read of env_acc (used only if ws too small)
__global__ void k_mean2(float* __restrict__ out, const float* __restrict__ ws,
                        size_t cnt_off) {
    __shared__ float wsum[4];
    int blk = blockIdx.x;                 // (b*3+c)*NG + g
    int b   = blk / (3 * NG);
    int t   = threadIdx.x;

    const float4* r4 = (const float4*)(out + OFF_ACC + (size_t)blk * NPIX);
    float s = 0.0f;
    for (int i = t; i < NPIX / 4; i += 256) {
        float4 v = r4[i];
        s += v.x + v.y + v.z + v.w;
    }
    for (int off = 32; off > 0; off >>= 1) s += __shfl_down(s, off);
    if ((t & 63) == 0) wsum[t >> 6] = s;
    __syncthreads();
    if (t == 0) {
        int rc = blk - b * 3 * NG;
        int c  = rc / NG;
        int g  = rc - c * NG;
        float tot = wsum[0] + wsum[1] + wsum[2] + wsum[3];
        out[OFF_MEAN + ((size_t)b * NG + g) * 3 + c] = tot / (ws[cnt_off + b] + 1e-6f);
    }
}

}  // namespace

extern "C" void kernel_launch(void* const* d_in, const int* in_sizes, int n_in,
                              void* d_out, int out_size, void* d_ws, size_t ws_size,
                              hipStream_t stream) {
    (void)in_sizes; (void)n_in; (void)out_size;
    const float* normalPred = (const float*)d_in[0];
    const float* depthPred  = (const float*)d_in[1];
    const float* env        = (const float*)d_in[2];
    const float* K          = (const float*)d_in[3];
    const float* verts      = (const float*)d_in[4];
    float* out = (float*)d_out;
    float* ws  = (float*)d_ws;

    const bool big = ws_size >= WS_NEED_HI;
    const size_t cnt_off = big ? WS_CNT_HI : WS_CNT_LO;

    k_points_zero<<<(NB * IMH * IMW + 255) / 256, 256, 0, stream>>>(depthPred, K, out, ws, cnt_off);
    k_prep<<<(NB * NPIX + 255) / 256, 256, 0, stream>>>(normalPred, depthPred, K, out, ws, cnt_off);
    if (big) {
        k_env<true><<<NB * TILES, 256, 0, stream>>>(env, verts, out, ws);
        k_psum<<<NB * NG * 3, 64, 0, stream>>>(out, ws, cnt_off);
    } else {
        k_env<false><<<NB * TILES, 256, 0, stream>>>(env, verts, out, ws);
        k_mean2<<<NB * 3 * NG, 256, 0, stream>>>(out, ws, cnt_off);
    }
}

// Round 16
// 109.296 us; speedup vs baseline: 1.2401x; 1.0092x over previous
//
#include <hip/hip_runtime.h>
#include <math.h>

namespace {

constexpr int IMH = 240, IMW = 320;
constexpr int ER = 120, EC = 160, EH = 8, EW = 16;
constexpr int NG = 384;            // 6*8*8
constexpr int NPIX = ER * EC;      // 19200
constexpr int NB = 2;
constexpr int NTAP = EH * EW;      // 128

// d_out offsets (floats): (env_acc, env_mean, points, mask, vec_to_t)
constexpr size_t ACC_N    = (size_t)NB * 3 * NG * NPIX;
constexpr size_t OFF_ACC  = 0;
constexpr size_t OFF_MEAN = OFF_ACC + ACC_N;
constexpr size_t MEAN_N   = (size_t)NB * NG * 3;
constexpr size_t OFF_PTS  = OFF_MEAN + MEAN_N;
constexpr size_t PTS_N    = (size_t)NB * 3 * IMH * IMW;
constexpr size_t OFF_MASK = OFF_PTS + PTS_N;
constexpr size_t MASK_N   = (size_t)NB * NPIX;
constexpr size_t OFF_VEC  = OFF_MASK + MASK_N;

// k_env geometry: 32 px per block (bf16 env tile in LDS), 8 g-lanes,
// interleaved g-walk (g = it*GLN + glane)
constexpr int TPX   = 32;
constexpr int GLN   = 8;
constexpr int GIT   = NG / GLN;           // 48
constexpr int TILES = NPIX / TPX;         // 600
constexpr int LROW  = 3 * NTAP + 4;       // 388 shorts per px row (24.8 KB tile)

// d_ws offsets (floats)
constexpr size_t WS_S     = (size_t)NB * NPIX;              // 38400
constexpr size_t WS_INVA  = 0;                              // 9 planes
constexpr size_t WS_PTS   = WS_INVA + 9 * WS_S;             // 3 planes
constexpr size_t WS_PART  = WS_PTS + 3 * WS_S;              // 2304*600 partials
constexpr size_t PART_N   = (size_t)NB * NG * 3 * TILES;    // 1,382,400
constexpr size_t WS_CNT_HI = WS_PART + PART_N;
constexpr size_t WS_CNT_LO = WS_PART;
constexpr size_t WS_NEED_HI = (WS_CNT_HI + NB) * 4;         // bytes

typedef float f32x3 __attribute__((ext_vector_type(3), aligned(4)));
typedef float f32x4 __attribute__((ext_vector_type(4)));

__device__ __forceinline__ float fpix_of(const float* K, int b) {
    return K[b * 9 + 0] * (IMW * 0.5f) / K[b * 9 + 2];
}

__device__ __forceinline__ unsigned bf16r(float f) {
    unsigned b = __float_as_uint(f);
    return (b + 0x7FFFu + ((b >> 16) & 1u)) >> 16;
}
__device__ __forceinline__ float bfload(unsigned short u) {
    return __uint_as_float((unsigned)u << 16);
}

// DPP add with compile-time control constants
template <int CTRL, int RMASK>
__device__ __forceinline__ float dpp_add(float s) {
    int t = __builtin_amdgcn_update_dpp(0, __float_as_int(s), CTRL, RMASK, 0xf, true);
    return s + __int_as_float(t);
}
// half-wave (32-lane) sum, pure VALU: result in lanes 31 and 63
__device__ __forceinline__ float hw_sum(float s) {
    s = dpp_add<0x111, 0xf>(s);   // row_shr:1
    s = dpp_add<0x112, 0xf>(s);   // row_shr:2
    s = dpp_add<0x114, 0xf>(s);   // row_shr:4
    s = dpp_add<0x118, 0xf>(s);   // row_shr:8 -> lane15/31/47/63 = row sums
    s = dpp_add<0x142, 0xa>(s);   // row_bcast:15 into rows 1,3
    return s;                     // lane31 = rows0+1, lane63 = rows2+3
}

// el = acos(x) * 16/pi  (poly coeffs pre-scaled)
__device__ __forceinline__ float acos_el(float x) {
    float ax = fminf(fabsf(x), 1.0f);
    float p  = fmaf(fmaf(fmaf(-0.09538315f, ax, 0.37820512f), ax, -1.08021632f),
                    ax, 7.99996873f);
    float r  = sqrtf(1.0f - ax) * p;
    return (x >= 0.0f) ? r : 16.0f - r;
}

// az = 8 + atan2(y,x)*8/pi  (coeffs pre-scaled)
__device__ __forceinline__ float atan2_az(float y, float x) {
    float ay = fabsf(y), ax = fabsf(x);
    float mn = fminf(ax, ay), mx = fmaxf(ax, ay);
    float a  = mn * __builtin_amdgcn_rcpf(fmaxf(mx, 1e-37f));
    float s  = a * a;
    float r  = a * fmaf(s, fmaf(s, fmaf(s, fmaf(s, 0.05305631f, -0.21677864f),
                                        0.45872349f), -0.84104627f), 2.54613763f);
    if (ay > ax) r = 4.0f - r;
    if (x < 0.0f) r = 8.0f - r;
    return fmaf(copysignf(1.0f, y), r, 8.0f);
}

// Fused: points (600 blocks' worth) + per-env-pixel prep (first 150 blocks)
__global__ void k_prep2(const float* __restrict__ normal,
                        const float* __restrict__ depth,
                        const float* __restrict__ K,
                        float* __restrict__ out,
                        float* __restrict__ ws, size_t cnt_off) {
    int t   = threadIdx.x;
    int blk = blockIdx.x;
    int idx = blk * 256 + t;
    if (blk == 0 && t < NB) ws[cnt_off + t] = 0.0f;

    // ---- points (full res) ----
    {
        int b  = idx / (IMH * IMW);
        int pp = idx - b * (IMH * IMW);
        int v  = pp / IMW;
        int u  = pp - v * IMW;
        float fp = fpix_of(K, b);
        float z  = -depth[idx];
        float x  = -(((float)u - IMW * 0.5f) / fp) * z;
        float y  =  (((float)v - IMH * 0.5f) / fp) * z;
        float* P = out + OFF_PTS + (size_t)b * 3 * IMH * IMW;
        __builtin_nontemporal_store(x, P + pp);
        __builtin_nontemporal_store(y, P + pp + IMH * IMW);
        __builtin_nontemporal_store(z, P + pp + 2 * IMH * IMW);
    }

    // ---- prep (env-res, first 150 blocks) ----
    if (blk >= (NB * NPIX) / 256) return;
    {
        int b   = idx / NPIX;
        int pix = idx - b * NPIX;
        int h   = pix / EC;
        int w   = pix - h * EC;
        int v = 2 * h, u = 2 * w;

        float fp = fpix_of(K, b);
        float z  = -depth[(size_t)b * IMH * IMW + (size_t)v * IMW + u];
        float px = -(((float)u - 160.0f) / fp) * z;
        float py =  (((float)v - 120.0f) / fp) * z;

        ws[WS_PTS + 0 * WS_S + idx] = px;
        ws[WS_PTS + 1 * WS_S + idx] = py;
        ws[WS_PTS + 2 * WS_S + idx] = z;

        float m = (z < -0.1f) ? 1.0f : 0.0f;
        __builtin_nontemporal_store(m, out + OFF_MASK + idx);
        float cm = m;
        for (int off = 32; off > 0; off >>= 1) cm += __shfl_down(cm, off);
        if ((t & 63) == 0) atomicAdd(&ws[cnt_off + b], cm);

        float n[3];
#pragma unroll
        for (int c = 0; c < 3; ++c) {
            const float* Nc = normal + ((size_t)(b * 3 + c) * IMH + v) * IMW + u;
            n[c] = 0.25f * (Nc[0] + Nc[1] + Nc[IMW] + Nc[IMW + 1]);
        }
        float nl = sqrtf(n[0]*n[0] + n[1]*n[1] + n[2]*n[2]) + 1e-6f;
        float nx = n[0] / nl, ny = n[1] / nl, nz = n[2] / nl;

        float t0 = -ny * nx, t1 = 1.0f - ny * ny, t2 = -ny * nz;
        float tl = sqrtf(t0*t0 + t1*t1 + t2*t2) + 1e-6f;
        float cy0 = t0 / tl, cy1 = t1 / tl, cy2 = t2 / tl;

        float cr0 = cy1 * nz - cy2 * ny;
        float cr1 = cy2 * nx - cy0 * nz;
        float cr2 = cy0 * ny - cy1 * nx;
        float cl = sqrtf(cr0*cr0 + cr1*cr1 + cr2*cr2) + 1e-6f;
        float cx0 = -cr0 / cl, cx1 = -cr1 / cl, cx2 = -cr2 / cl;

        float a00 = cx0 + 1e-6f, a01 = cy0,         a02 = nx;
        float a10 = cx1,         a11 = cy1 + 1e-6f, a12 = ny;
        float a20 = cx2,         a21 = cy2,         a22 = nz + 1e-6f;

        float c00 =  a11 * a22 - a12 * a21;
        float c01 = -(a10 * a22 - a12 * a20);
        float c02 =  a10 * a21 - a11 * a20;
        float det = a00 * c00 + a01 * c01 + a02 * c02;
        float id  = 1.0f / det;

        ws[WS_INVA + 0 * WS_S + idx] = c00 * id;
        ws[WS_INVA + 1 * WS_S + idx] = (a02 * a21 - a01 * a22) * id;
        ws[WS_INVA + 2 * WS_S + idx] = (a01 * a12 - a02 * a11) * id;
        ws[WS_INVA + 3 * WS_S + idx] = c01 * id;
        ws[WS_INVA + 4 * WS_S + idx] = (a00 * a22 - a02 * a20) * id;
        ws[WS_INVA + 5 * WS_S + idx] = (a02 * a10 - a00 * a12) * id;
        ws[WS_INVA + 6 * WS_S + idx] = c02 * id;
        ws[WS_INVA + 7 * WS_S + idx] = (a01 * a20 - a00 * a21) * id;
        ws[WS_INVA + 8 * WS_S + idx] = (a00 * a11 - a01 * a10) * id;
    }
}

template <bool WP>
__global__ void __launch_bounds__(256) k_env(const float* __restrict__ env,
                       const float* __restrict__ verts,
                       float* __restrict__ out,
                       float* __restrict__ ws) {
    __shared__ unsigned short lds16[TPX * LROW];   // bf16 env tile, 24.8 KB

    int blk  = blockIdx.x;
    int b    = blk / TILES;
    int tile = blk - b * TILES;
    int px0  = tile * TPX;
    int t    = threadIdx.x;

    // ---- stage env tile (3ch x 32px x 128 taps) as bf16, nt loads ----
    {
        const float* ebase = env + (size_t)b * 3 * NPIX * NTAP + (size_t)px0 * NTAP;
#pragma unroll
        for (int it = 0; it < 12; ++it) {
            int f   = (it * 256 + t) * 4;      // dword index in tile
            int c   = f >> 12;
            int r   = f & 4095;
            f32x4 v4 = __builtin_nontemporal_load(
                (const f32x4*)(ebase + (size_t)c * NPIX * NTAP + r));
            ushort4 u4;
            u4.x = (unsigned short)bf16r(v4.x); u4.y = (unsigned short)bf16r(v4.y);
            u4.z = (unsigned short)bf16r(v4.z); u4.w = (unsigned short)bf16r(v4.w);
            int j   = r >> 7;
            int tap = r & 127;
            *(ushort4*)(&lds16[j * LROW + c * NTAP + tap]) = u4;
        }
    }
    __syncthreads();

    int px_l  = t & 31;
    int glane = t >> 5;          // 0..7
    int pix   = px0 + px_l;
    int bp    = b * NPIX + pix;
    int row   = px_l * LROW;

    float px = ws[WS_PTS + 0 * WS_S + bp];
    float py = ws[WS_PTS + 1 * WS_S + bp];
    float pz = ws[WS_PTS + 2 * WS_S + bp];
    float i00 = ws[WS_INVA + 0 * WS_S + bp];
    float i01 = ws[WS_INVA + 1 * WS_S + bp];
    float i02 = ws[WS_INVA + 2 * WS_S + bp];
    float i10 = ws[WS_INVA + 3 * WS_S + bp];
    float i11 = ws[WS_INVA + 4 * WS_S + bp];
    float i12 = ws[WS_INVA + 5 * WS_S + bp];
    float i20 = ws[WS_INVA + 6 * WS_S + bp];
    float i21 = ws[WS_INVA + 7 * WS_S + bp];
    float i22 = ws[WS_INVA + 8 * WS_S + bp];
    float m = (pz < -0.1f) ? 1.0f : 0.0f;

    // interleaved g-walk: 8 half-waves cover 8 adjacent g-planes
    int g0 = glane;
    const float* vp = verts + ((size_t)b * NG + g0) * 3;
    float* pA0 = out + OFF_ACC + ((size_t)(b * 3 + 0) * NG + g0) * NPIX + pix;
    float* pA1 = out + OFF_ACC + ((size_t)(b * 3 + 1) * NG + g0) * NPIX + pix;
    float* pA2 = out + OFF_ACC + ((size_t)(b * 3 + 2) * NG + g0) * NPIX + pix;
    float* pV  = out + OFF_VEC + (((size_t)b * NG + g0) * NPIX + pix) * 3;
    float* pP  = ws + WS_PART + ((size_t)(b * NG + g0) * 3) * TILES + tile;

#pragma unroll 2
    for (int it = 0; it < GIT; ++it) {
        float vx = vp[0] - px, vy = vp[1] - py, vz = vp[2] - pz;
        // one dwordx3 nt store (never re-read -> no L2 allocate)
        f32x3 v3; v3.x = vx; v3.y = vy; v3.z = vz;
        __builtin_nontemporal_store(v3, (f32x3*)pV);

        float l0 = i00 * vx + i01 * vy + i02 * vz;
        float l1 = i10 * vx + i11 * vy + i12 * vz;
        float l2 = i20 * vx + i21 * vy + i22 * vz;
        float nl = sqrtf(l0*l0 + l1*l1 + l2*l2) + 1e-6f;
        float l2n = l2 * __builtin_amdgcn_rcpf(nl);

        float el = acos_el(l2n);             // theta in grid units
        float az = atan2_az(l1, l0);         // phi in grid units

        float azf = __builtin_amdgcn_fmed3f(az - 0.5f, 0.0f, 15.0f);
        float elf = __builtin_amdgcn_fmed3f(el - 0.5f, 0.0f, 7.0f);
        float x0 = floorf(azf), y0 = floorf(elf);
        float fx = azf - x0,    fy = elf - y0;
        int x0i = (int)x0, y0i = (int)y0;
        int x1i = min(x0i + 1, 15);
        int y1i = min(y0i + 1, 7);

        float w00 = (1.0f - fx) * (1.0f - fy);
        float w01 = fx * (1.0f - fy);
        float w10 = (1.0f - fx) * fy;
        float w11 = fx * fy;

        int a00 = row + (y0i << 4) + x0i;
        int a01 = row + (y0i << 4) + x1i;
        int a10 = row + (y1i << 4) + x0i;
        int a11 = row + (y1i << 4) + x1i;

        float v0 = (bfload(lds16[a00]) * w00 + bfload(lds16[a01]) * w01 +
                    bfload(lds16[a10]) * w10 + bfload(lds16[a11]) * w11) * m;
        float v1 = (bfload(lds16[a00 + NTAP]) * w00 + bfload(lds16[a01 + NTAP]) * w01 +
                    bfload(lds16[a10 + NTAP]) * w10 + bfload(lds16[a11 + NTAP]) * w11) * m;
        float v2 = (bfload(lds16[a00 + 2*NTAP]) * w00 + bfload(lds16[a01 + 2*NTAP]) * w01 +
                    bfload(lds16[a10 + 2*NTAP]) * w10 + bfload(lds16[a11 + 2*NTAP]) * w11) * m;

        __builtin_nontemporal_store(v0, pA0);
        __builtin_nontemporal_store(v1, pA1);
        __builtin_nontemporal_store(v2, pA2);

        if constexpr (WP) {
            // half-wave pixel-sum via DPP (pure VALU); partials to unique slots
            float s0 = hw_sum(v0);
            float s1 = hw_sum(v1);
            float s2 = hw_sum(v2);
            if ((t & 31) == 31) {
                pP[0 * TILES] = s0;
                pP[1 * TILES] = s1;
                pP[2 * TILES] = s2;
            }
            pP += (size_t)GLN * 3 * TILES;
        }

        vp  += 3 * GLN;
        pV  += (size_t)GLN * NPIX * 3;
        pA0 += (size_t)GLN * NPIX;
        pA1 += (size_t)GLN * NPIX;
        pA2 += (size_t)GLN * NPIX;
    }
}

// reduce 600 tile-partials per (b,g,c); one wave per output
__global__ void k_psum(float* __restrict__ out, const float* __restrict__ ws,
                       size_t cnt_off) {
    int r = blockIdx.x;                 // (b*NG+g)*3+c
    int l = threadIdx.x;                // 0..63
    const float* p = ws + WS_PART + (size_t)r * TILES;
    float s = 0.0f;
    for (int i = l; i < TILES; i += 64) s += p[i];
#pragma unroll
    for (int off = 32; off > 0; off >>= 1) s += __shfl_down(s, off);
    if (l == 0) {
        int b = r / (NG * 3);
        out[OFF_MEAN + r] = s / (ws[cnt_off + b] + 1e-6f);
    }
}

// fallback: mean via re-read of env_acc (used only if ws too small)
__global__ void k_mean2(float* __restrict__ out, const float* __restrict__ ws,
                        size_t cnt_off) {
    __shared__ float wsum[4];
    int blk = blockIdx.x;                 // (b*3+c)*NG + g
    int b   = blk / (3 * NG);
    int t   = threadIdx.x;

    const float4* r4 = (const float4*)(out + OFF_ACC + (size_t)blk * NPIX);
    float s = 0.0f;
    for (int i = t; i < NPIX / 4; i += 256) {
        float4 v = r4[i];
        s += v.x + v.y + v.z + v.w;
    }
    for (int off = 32; off > 0; off >>= 1) s += __shfl_down(s, off);
    if ((t & 63) == 0) wsum[t >> 6] = s;
    __syncthreads();
    if (t == 0) {
        int rc = blk - b * 3 * NG;
        int c  = rc / NG;
        int g  = rc - c * NG;
        float tot = wsum[0] + wsum[1] + wsum[2] + wsum[3];
        out[OFF_MEAN + ((size_t)b * NG + g) * 3 + c] = tot / (ws[cnt_off + b] + 1e-6f);
    }
}

}  // namespace

extern "C" void kernel_launch(void* const* d_in, const int* in_sizes, int n_in,
                              void* d_out, int out_size, void* d_ws, size_t ws_size,
                              hipStream_t stream) {
    (void)in_sizes; (void)n_in; (void)out_size;
    const float* normalPred = (const float*)d_in[0];
    const float* depthPred  = (const float*)d_in[1];
    const float* env        = (const float*)d_in[2];
    const float* K          = (const float*)d_in[3];
    const float* verts      = (const float*)d_in[4];
    float* out = (float*)d_out;
    float* ws  = (float*)d_ws;

    const bool big = ws_size >= WS_NEED_HI;
    const size_t cnt_off = big ? WS_CNT_HI : WS_CNT_LO;

    k_prep2<<<(NB * IMH * IMW) / 256, 256, 0, stream>>>(normalPred, depthPred, K, out, ws, cnt_off);
    if (big) {
        k_env<true><<<NB * TILES, 256, 0, stream>>>(env, verts, out, ws);
        k_psum<<<NB * NG * 3, 64, 0, stream>>>(out, ws, cnt_off);
    } else {
        k_env<false><<<NB * TILES, 256, 0, stream>>>(env, verts, out, ws);
        k_mean2<<<NB * 3 * NG, 256, 0, stream>>>(out, ws, cnt_off);
    }
}

// Round 17
// 100.647 us; speedup vs baseline: 1.3466x; 1.0859x over previous
//
#include <hip/hip_runtime.h>
#include <math.h>

namespace {

constexpr int IMH = 240, IMW = 320;
constexpr int ER = 120, EC = 160, EH = 8, EW = 16;
constexpr int NG = 384;            // 6*8*8
constexpr int NPIX = ER * EC;      // 19200
constexpr int NB = 2;
constexpr int NTAP = EH * EW;      // 128

// d_out offsets (floats): (env_acc, env_mean, points, mask, vec_to_t)
constexpr size_t ACC_N    = (size_t)NB * 3 * NG * NPIX;
constexpr size_t OFF_ACC  = 0;
constexpr size_t OFF_MEAN = OFF_ACC + ACC_N;
constexpr size_t MEAN_N   = (size_t)NB * NG * 3;
constexpr size_t OFF_PTS  = OFF_MEAN + MEAN_N;
constexpr size_t PTS_N    = (size_t)NB * 3 * IMH * IMW;
constexpr size_t OFF_MASK = OFF_PTS + PTS_N;
constexpr size_t MASK_N   = (size_t)NB * NPIX;
constexpr size_t OFF_VEC  = OFF_MASK + MASK_N;

// k_env geometry: 32 px per block (bf16 env tile in LDS), 8 g-lanes,
// interleaved g-walk (g = it*GLN + glane). 1200 blocks total.
constexpr int TPX   = 32;
constexpr int GLN   = 8;
constexpr int GIT   = NG / GLN;           // 48
constexpr int TILES = NPIX / TPX;         // 600 per b
constexpr int NBLK  = NB * TILES;         // 1200
constexpr int LROW  = 3 * NTAP + 4;       // 388 shorts per px row (24.8 KB tile)

// d_ws offsets (floats)
// big path:  [0, PART_N) tile partials, [PART_N, PART_N+NBLK) mask-count parts
// small path: [0, NBLK) mask-count parts only
constexpr size_t WS_PART   = 0;
constexpr size_t PART_N    = (size_t)NB * NG * 3 * TILES;    // 1,382,400
constexpr size_t WS_CNTP_HI = PART_N;
constexpr size_t WS_CNTP_LO = 0;
constexpr size_t WS_NEED_HI = (PART_N + NBLK) * 4;           // bytes

typedef float f32x3 __attribute__((ext_vector_type(3), aligned(4)));
typedef float f32x4 __attribute__((ext_vector_type(4)));

__device__ __forceinline__ float fpix_of(const float* K, int b) {
    return K[b * 9 + 0] * (IMW * 0.5f) / K[b * 9 + 2];
}

__device__ __forceinline__ unsigned bf16r(float f) {
    unsigned b = __float_as_uint(f);
    return (b + 0x7FFFu + ((b >> 16) & 1u)) >> 16;
}
__device__ __forceinline__ float bfload(unsigned short u) {
    return __uint_as_float((unsigned)u << 16);
}

// DPP add with compile-time control constants
template <int CTRL, int RMASK>
__device__ __forceinline__ float dpp_add(float s) {
    int t = __builtin_amdgcn_update_dpp(0, __float_as_int(s), CTRL, RMASK, 0xf, true);
    return s + __int_as_float(t);
}
// half-wave (32-lane) sum, pure VALU: result in lanes 31 and 63
__device__ __forceinline__ float hw_sum(float s) {
    s = dpp_add<0x111, 0xf>(s);   // row_shr:1
    s = dpp_add<0x112, 0xf>(s);   // row_shr:2
    s = dpp_add<0x114, 0xf>(s);   // row_shr:4
    s = dpp_add<0x118, 0xf>(s);   // row_shr:8 -> lane15/31/47/63 = row sums
    s = dpp_add<0x142, 0xa>(s);   // row_bcast:15 into rows 1,3
    return s;                     // lane31 = rows0+1, lane63 = rows2+3
}

// el = acos(x) * 16/pi  (poly coeffs pre-scaled)
__device__ __forceinline__ float acos_el(float x) {
    float ax = fminf(fabsf(x), 1.0f);
    float p  = fmaf(fmaf(fmaf(-0.09538315f, ax, 0.37820512f), ax, -1.08021632f),
                    ax, 7.99996873f);
    float r  = sqrtf(1.0f - ax) * p;
    return (x >= 0.0f) ? r : 16.0f - r;
}

// az = 8 + atan2(y,x)*8/pi  (coeffs pre-scaled)
__device__ __forceinline__ float atan2_az(float y, float x) {
    float ay = fabsf(y), ax = fabsf(x);
    float mn = fminf(ax, ay), mx = fmaxf(ax, ay);
    float a  = mn * __builtin_amdgcn_rcpf(fmaxf(mx, 1e-37f));
    float s  = a * a;
    float r  = a * fmaf(s, fmaf(s, fmaf(s, fmaf(s, 0.05305631f, -0.21677864f),
                                        0.45872349f), -0.84104627f), 2.54613763f);
    if (ay > ax) r = 4.0f - r;
    if (x < 0.0f) r = 8.0f - r;
    return fmaf(copysignf(1.0f, y), r, 8.0f);
}

template <bool WP>
__global__ void __launch_bounds__(256) k_env(const float* __restrict__ env,
                       const float* __restrict__ verts,
                       const float* __restrict__ normal,
                       const float* __restrict__ depth,
                       const float* __restrict__ K,
                       float* __restrict__ out,
                       float* __restrict__ ws, size_t cntp_off) {
    __shared__ unsigned short lds16[TPX * LROW];   // bf16 env tile, 24.8 KB
    __shared__ float lprep[12 * TPX];              // [0..2]=pts, [3..11]=invA

    int blk  = blockIdx.x;
    int b    = blk / TILES;
    int tile = blk - b * TILES;
    int px0  = tile * TPX;
    int t    = threadIdx.x;

    // ---- fused prologue: points (threads 0..127), prep (threads 0..31),
    //      env staging (all 256) — all before one __syncthreads ----

    // points: 1200 blocks x 128 threads = 153,600 = NB*IMH*IMW
    if (t < 128) {
        int idx = blk * 128 + t;
        int bb  = idx / (IMH * IMW);
        int pp  = idx - bb * (IMH * IMW);
        int v   = pp / IMW;
        int u   = pp - v * IMW;
        float fp = fpix_of(K, bb);
        float z  = -depth[idx];
        float x  = -(((float)u - IMW * 0.5f) / fp) * z;
        float y  =  (((float)v - IMH * 0.5f) / fp) * z;
        float* P = out + OFF_PTS + (size_t)bb * 3 * IMH * IMW;
        __builtin_nontemporal_store(x, P + pp);
        __builtin_nontemporal_store(y, P + pp + IMH * IMW);
        __builtin_nontemporal_store(z, P + pp + 2 * IMH * IMW);
    }

    // prep for this block's 32 env pixels -> LDS (+ mask out, + count slot)
    if (t < TPX) {
        int pix = px0 + t;
        int h   = pix / EC;
        int w   = pix - h * EC;
        int v = 2 * h, u = 2 * w;

        float fp = fpix_of(K, b);
        float z  = -depth[(size_t)b * IMH * IMW + (size_t)v * IMW + u];
        float px = -(((float)u - 160.0f) / fp) * z;
        float py =  (((float)v - 120.0f) / fp) * z;

        lprep[0 * TPX + t] = px;
        lprep[1 * TPX + t] = py;
        lprep[2 * TPX + t] = z;

        float m = (z < -0.1f) ? 1.0f : 0.0f;
        __builtin_nontemporal_store(m, out + OFF_MASK + (size_t)b * NPIX + pix);
        float cm = hw_sum(m);                 // lane31 = sum of lanes 0..31
        if (t == 31) ws[cntp_off + blk] = cm; // unique slot: no zeroing needed

        float n[3];
#pragma unroll
        for (int c = 0; c < 3; ++c) {
            const float* Nc = normal + ((size_t)(b * 3 + c) * IMH + v) * IMW + u;
            n[c] = 0.25f * (Nc[0] + Nc[1] + Nc[IMW] + Nc[IMW + 1]);
        }
        float nl = sqrtf(n[0]*n[0] + n[1]*n[1] + n[2]*n[2]) + 1e-6f;
        float nx = n[0] / nl, ny = n[1] / nl, nz = n[2] / nl;

        float t0 = -ny * nx, t1 = 1.0f - ny * ny, t2 = -ny * nz;
        float tl = sqrtf(t0*t0 + t1*t1 + t2*t2) + 1e-6f;
        float cy0 = t0 / tl, cy1 = t1 / tl, cy2 = t2 / tl;

        float cr0 = cy1 * nz - cy2 * ny;
        float cr1 = cy2 * nx - cy0 * nz;
        float cr2 = cy0 * ny - cy1 * nx;
        float cl = sqrtf(cr0*cr0 + cr1*cr1 + cr2*cr2) + 1e-6f;
        float cx0 = -cr0 / cl, cx1 = -cr1 / cl, cx2 = -cr2 / cl;

        float a00 = cx0 + 1e-6f, a01 = cy0,         a02 = nx;
        float a10 = cx1,         a11 = cy1 + 1e-6f, a12 = ny;
        float a20 = cx2,         a21 = cy2,         a22 = nz + 1e-6f;

        float c00 =  a11 * a22 - a12 * a21;
        float c01 = -(a10 * a22 - a12 * a20);
        float c02 =  a10 * a21 - a11 * a20;
        float det = a00 * c00 + a01 * c01 + a02 * c02;
        float id  = 1.0f / det;

        lprep[ 3 * TPX + t] = c00 * id;
        lprep[ 4 * TPX + t] = (a02 * a21 - a01 * a22) * id;
        lprep[ 5 * TPX + t] = (a01 * a12 - a02 * a11) * id;
        lprep[ 6 * TPX + t] = c01 * id;
        lprep[ 7 * TPX + t] = (a00 * a22 - a02 * a20) * id;
        lprep[ 8 * TPX + t] = (a02 * a10 - a00 * a12) * id;
        lprep[ 9 * TPX + t] = c02 * id;
        lprep[10 * TPX + t] = (a01 * a20 - a00 * a21) * id;
        lprep[11 * TPX + t] = (a00 * a11 - a01 * a10) * id;
    }

    // ---- stage env tile (3ch x 32px x 128 taps) as bf16, nt loads ----
    {
        const float* ebase = env + (size_t)b * 3 * NPIX * NTAP + (size_t)px0 * NTAP;
#pragma unroll
        for (int it = 0; it < 12; ++it) {
            int f   = (it * 256 + t) * 4;      // dword index in tile
            int c   = f >> 12;
            int r   = f & 4095;
            f32x4 v4 = __builtin_nontemporal_load(
                (const f32x4*)(ebase + (size_t)c * NPIX * NTAP + r));
            ushort4 u4;
            u4.x = (unsigned short)bf16r(v4.x); u4.y = (unsigned short)bf16r(v4.y);
            u4.z = (unsigned short)bf16r(v4.z); u4.w = (unsigned short)bf16r(v4.w);
            int j   = r >> 7;
            int tap = r & 127;
            *(ushort4*)(&lds16[j * LROW + c * NTAP + tap]) = u4;
        }
    }
    __syncthreads();

    int px_l  = t & 31;
    int glane = t >> 5;          // 0..7
    int pix   = px0 + px_l;
    int row   = px_l * LROW;

    float px = lprep[0 * TPX + px_l];
    float py = lprep[1 * TPX + px_l];
    float pz = lprep[2 * TPX + px_l];
    float i00 = lprep[ 3 * TPX + px_l];
    float i01 = lprep[ 4 * TPX + px_l];
    float i02 = lprep[ 5 * TPX + px_l];
    float i10 = lprep[ 6 * TPX + px_l];
    float i11 = lprep[ 7 * TPX + px_l];
    float i12 = lprep[ 8 * TPX + px_l];
    float i20 = lprep[ 9 * TPX + px_l];
    float i21 = lprep[10 * TPX + px_l];
    float i22 = lprep[11 * TPX + px_l];
    float m = (pz < -0.1f) ? 1.0f : 0.0f;

    // interleaved g-walk: 8 half-waves cover 8 adjacent g-planes
    int g0 = glane;
    const float* vp = verts + ((size_t)b * NG + g0) * 3;
    float* pA0 = out + OFF_ACC + ((size_t)(b * 3 + 0) * NG + g0) * NPIX + pix;
    float* pA1 = out + OFF_ACC + ((size_t)(b * 3 + 1) * NG + g0) * NPIX + pix;
    float* pA2 = out + OFF_ACC + ((size_t)(b * 3 + 2) * NG + g0) * NPIX + pix;
    float* pV  = out + OFF_VEC + (((size_t)b * NG + g0) * NPIX + pix) * 3;
    float* pP  = ws + WS_PART + ((size_t)(b * NG + g0) * 3) * TILES + tile;

#pragma unroll 2
    for (int it = 0; it < GIT; ++it) {
        float vx = vp[0] - px, vy = vp[1] - py, vz = vp[2] - pz;
        f32x3 v3; v3.x = vx; v3.y = vy; v3.z = vz;
        __builtin_nontemporal_store(v3, (f32x3*)pV);

        float l0 = i00 * vx + i01 * vy + i02 * vz;
        float l1 = i10 * vx + i11 * vy + i12 * vz;
        float l2 = i20 * vx + i21 * vy + i22 * vz;
        float nl = sqrtf(l0*l0 + l1*l1 + l2*l2) + 1e-6f;
        float l2n = l2 * __builtin_amdgcn_rcpf(nl);

        float el = acos_el(l2n);             // theta in grid units
        float az = atan2_az(l1, l0);         // phi in grid units

        float azf = __builtin_amdgcn_fmed3f(az - 0.5f, 0.0f, 15.0f);
        float elf = __builtin_amdgcn_fmed3f(el - 0.5f, 0.0f, 7.0f);
        float x0 = floorf(azf), y0 = floorf(elf);
        float fx = azf - x0,    fy = elf - y0;
        int x0i = (int)x0, y0i = (int)y0;
        int x1i = min(x0i + 1, 15);
        int y1i = min(y0i + 1, 7);

        float w00 = (1.0f - fx) * (1.0f - fy);
        float w01 = fx * (1.0f - fy);
        float w10 = (1.0f - fx) * fy;
        float w11 = fx * fy;

        int a00 = row + (y0i << 4) + x0i;
        int a01 = row + (y0i << 4) + x1i;
        int a10 = row + (y1i << 4) + x0i;
        int a11 = row + (y1i << 4) + x1i;

        float v0 = (bfload(lds16[a00]) * w00 + bfload(lds16[a01]) * w01 +
                    bfload(lds16[a10]) * w10 + bfload(lds16[a11]) * w11) * m;
        float v1 = (bfload(lds16[a00 + NTAP]) * w00 + bfload(lds16[a01 + NTAP]) * w01 +
                    bfload(lds16[a10 + NTAP]) * w10 + bfload(lds16[a11 + NTAP]) * w11) * m;
        float v2 = (bfload(lds16[a00 + 2*NTAP]) * w00 + bfload(lds16[a01 + 2*NTAP]) * w01 +
                    bfload(lds16[a10 + 2*NTAP]) * w10 + bfload(lds16[a11 + 2*NTAP]) * w11) * m;

        __builtin_nontemporal_store(v0, pA0);
        __builtin_nontemporal_store(v1, pA1);
        __builtin_nontemporal_store(v2, pA2);

        if constexpr (WP) {
            float s0 = hw_sum(v0);
            float s1 = hw_sum(v1);
            float s2 = hw_sum(v2);
            if ((t & 31) == 31) {
                pP[0 * TILES] = s0;
                pP[1 * TILES] = s1;
                pP[2 * TILES] = s2;
            }
            pP += (size_t)GLN * 3 * TILES;
        }

        vp  += 3 * GLN;
        pV  += (size_t)GLN * NPIX * 3;
        pA0 += (size_t)GLN * NPIX;
        pA1 += (size_t)GLN * NPIX;
        pA2 += (size_t)GLN * NPIX;
    }
}

// reduce 600 tile-partials + 600 count-parts per (b,g,c); one wave per output
__global__ void k_psum(float* __restrict__ out, const float* __restrict__ ws,
                       size_t cntp_off) {
    int r = blockIdx.x;                 // (b*NG+g)*3+c
    int l = threadIdx.x;                // 0..63
    int b = r / (NG * 3);
    const float* p  = ws + WS_PART + (size_t)r * TILES;
    const float* cp = ws + cntp_off + (size_t)b * TILES;
    float s = 0.0f, c = 0.0f;
    for (int i = l; i < TILES; i += 64) { s += p[i]; c += cp[i]; }
#pragma unroll
    for (int off = 32; off > 0; off >>= 1) {
        s += __shfl_down(s, off);
        c += __shfl_down(c, off);
    }
    if (l == 0) out[OFF_MEAN + r] = s / (c + 1e-6f);
}

// fallback: mean via re-read of env_acc (used only if ws too small)
__global__ void k_mean2(float* __restrict__ out, const float* __restrict__ ws,
                        size_t cntp_off) {
    __shared__ float wsum[8];
    int blk = blockIdx.x;                 // (b*3+c)*NG + g
    int b   = blk / (3 * NG);
    int t   = threadIdx.x;

    const float4* r4 = (const float4*)(out + OFF_ACC + (size_t)blk * NPIX);
    float s = 0.0f;
    for (int i = t; i < NPIX / 4; i += 256) {
        float4 v = r4[i];
        s += v.x + v.y + v.z + v.w;
    }
    const float* cp = ws + cntp_off + (size_t)b * TILES;
    float c = 0.0f;
    for (int i = t; i < TILES; i += 256) c += cp[i];
    for (int off = 32; off > 0; off >>= 1) {
        s += __shfl_down(s, off);
        c += __shfl_down(c, off);
    }
    if ((t & 63) == 0) { wsum[t >> 6] = s; wsum[4 + (t >> 6)] = c; }
    __syncthreads();
    if (t == 0) {
        int rc = blk - b * 3 * NG;
        int ch = rc / NG;
        int g  = rc - ch * NG;
        float tot = wsum[0] + wsum[1] + wsum[2] + wsum[3];
        float cnt = wsum[4] + wsum[5] + wsum[6] + wsum[7];
        out[OFF_MEAN + ((size_t)b * NG + g) * 3 + ch] = tot / (cnt + 1e-6f);
    }
}

}  // namespace

extern "C" void kernel_launch(void* const* d_in, const int* in_sizes, int n_in,
                              void* d_out, int out_size, void* d_ws, size_t ws_size,
                              hipStream_t stream) {
    (void)in_sizes; (void)n_in; (void)out_size;
    const float* normalPred = (const float*)d_in[0];
    const float* depthPred  = (const float*)d_in[1];
    const float* env        = (const float*)d_in[2];
    const float* K          = (const float*)d_in[3];
    const float* verts      = (const float*)d_in[4];
    float* out = (float*)d_out;
    float* ws  = (float*)d_ws;

    const bool big = ws_size >= WS_NEED_HI;
    const size_t cntp_off = big ? WS_CNTP_HI : WS_CNTP_LO;

    if (big) {
        k_env<true><<<NBLK, 256, 0, stream>>>(env, verts, normalPred, depthPred, K, out, ws, cntp_off);
        k_psum<<<NB * NG * 3, 64, 0, stream>>>(out, ws, cntp_off);
    } else {
        k_env<false><<<NBLK, 256, 0, stream>>>(env, verts, normalPred, depthPred, K, out, ws, cntp_off);
        k_mean2<<<NB * 3 * NG, 256, 0, stream>>>(out, ws, cntp_off);
    }
}